// Round 5
// baseline (653.915 us; speedup 1.0000x reference)
//
#include <hip/hip_runtime.h>

#define H 128          // hidden dim (fixed by problem)
#define CAP 64         // max edges per (rel,dst) bucket

typedef _Float16 f16x8 __attribute__((ext_vector_type(8)));
typedef float    f32x4 __attribute__((ext_vector_type(4)));

// ---------------- edge bucketing: one pass, reused by both layers ----------------
__global__ __launch_bounds__(256) void hist_fill(const int* __restrict__ src,
    const int* __restrict__ dst, const int* __restrict__ et,
    int* __restrict__ cnt, int* __restrict__ elist, int E, int N)
{
    int e = blockIdx.x * 256 + threadIdx.x;
    if (e >= E) return;
    int s = src[e], d = dst[e], t = et[e];
    int b = t * N + d;
    int pos = atomicAdd(&cnt[b], 1);
    if (pos < CAP) elist[(size_t)b * CAP + pos] = s;
}

// ---------------- weight prep: transpose + fp32->fp16 ----------------
__global__ __launch_bounds__(256) void prep_w(const float* __restrict__ w_in,
    const float* __restrict__ w_root, const float* __restrict__ w_rel,
    _Float16* __restrict__ wInT, _Float16* __restrict__ w3T, int K)
{
    int idx = blockIdx.x * 256 + threadIdx.x;
    int tot1 = K * H;
    if (idx < tot1) {
        int c = idx / K, k = idx - c * K;
        wInT[idx] = (_Float16)w_in[(size_t)k * H + c];
    } else {
        int i2 = idx - tot1;
        if (i2 < 3 * H * H) {
            int m = i2 / (H * H), r2 = i2 - m * (H * H);
            int c = r2 >> 7, k = r2 & 127;
            const float* s = (m == 0) ? w_root : (w_rel + (size_t)(m - 1) * H * H);
            w3T[i2] = (_Float16)s[(size_t)k * H + c];
        }
    }
}

__device__ __forceinline__ f16x8 cvt8(float4 v0, float4 v1) {
    f16x8 t;
    t[0] = (_Float16)v0.x; t[1] = (_Float16)v0.y; t[2] = (_Float16)v0.z; t[3] = (_Float16)v0.w;
    t[4] = (_Float16)v1.x; t[5] = (_Float16)v1.y; t[6] = (_Float16)v1.z; t[7] = (_Float16)v1.w;
    return t;
}

// ---------------- big MFMA GEMM: full-K B in registers, batched A loads ----------
// C16 = fp16(leakyrelu(A[M,768] @ W + b)). 512 threads = 8 waves; wave w owns
// output cols [w*16, w*16+16) with ALL 24 B-chunks resident in 96 VGPRs.
// Per 16-row m-tile: two half-passes, each batch-issuing 24 independent
// dwordx4 A-loads (24 KB/wave in flight) then cvt+MFMA. No LDS, no barriers.
__global__ __launch_bounds__(512, 2) void gemm_big(const float* __restrict__ A,
    const _Float16* __restrict__ WT, const float* __restrict__ bias,
    _Float16* __restrict__ C16, int M, int K, int mtiles)
{
    const int w   = threadIdx.x >> 6;   // 0..7 -> n-tile
    const int l   = threadIdx.x & 63;
    const int l15 = l & 15;
    const int q   = l >> 4;
    const int col = w * 16 + l15;

    // B fragments for the whole K (from L2-hot transposed weights)
    f16x8 bf[24];
    {
        const _Float16* bp = WT + (size_t)col * K + q * 8;
#pragma unroll
        for (int c = 0; c < 24; c++) bf[c] = *(const f16x8*)(bp + c * 32);
    }
    const float bj = bias[col];

    for (int t = blockIdx.x; t < mtiles; t += gridDim.x) {
        int arow = t * 16 + l15;
        if (arow >= M) arow = M - 1;             // clamp loads; stores predicated
        const float* ap = A + (size_t)arow * K + q * 8;

        f32x4 acc = {0.f, 0.f, 0.f, 0.f};
#pragma unroll 1
        for (int hp = 0; hp < 2; hp++) {         // two half-K passes, regs reused
            float4 av[24];
#pragma unroll
            for (int c = 0; c < 12; c++) {       // 24 independent loads, no deps
                av[2 * c]     = *(const float4*)(ap + (hp * 12 + c) * 32);
                av[2 * c + 1] = *(const float4*)(ap + (hp * 12 + c) * 32 + 4);
            }
#pragma unroll
            for (int c = 0; c < 12; c++) {
                f16x8 af = cvt8(av[2 * c], av[2 * c + 1]);
                acc = __builtin_amdgcn_mfma_f32_16x16x32_f16(af, bf[hp * 12 + c], acc, 0, 0, 0);
            }
        }

#pragma unroll
        for (int rg = 0; rg < 4; rg++) {
            int row = t * 16 + q * 4 + rg;
            if (row < M) {
                float v = acc[rg] + bj;
                v = (v >= 0.f) ? v : 0.01f * v;
                C16[(size_t)row * H + col] = (_Float16)v;
            }
        }
    }
}

// ---------------- fused per-layer GEMM: B3 in registers ---------------------------
// y = x@w_root + b (fp32); h_r = x@w_rel[r] (fp16). 256 threads = 4 waves of
// 16 cols; block LSB picks col-half. x-frag loads are 4 independent 16B reads.
__global__ __launch_bounds__(256) void gemm3(const _Float16* __restrict__ X16,
    const _Float16* __restrict__ W3, const float* __restrict__ bias,
    float* __restrict__ Y, _Float16* __restrict__ Hh, int M, int mtiles,
    size_t NH)
{
    const int w   = threadIdx.x >> 6;
    const int l   = threadIdx.x & 63;
    const int l15 = l & 15;
    const int q   = l >> 4;
    const int ch  = blockIdx.x & 1;
    const int col = ch * 64 + w * 16 + l15;

    f16x8 bf[3][4];
#pragma unroll
    for (int m = 0; m < 3; m++) {
        const _Float16* wp = W3 + (size_t)m * H * H + (size_t)col * H + q * 8;
#pragma unroll
        for (int c = 0; c < 4; c++) bf[m][c] = *(const f16x8*)(wp + c * 32);
    }
    const float bj = bias[col];

    for (int t = blockIdx.x >> 1; t < mtiles; t += (gridDim.x >> 1)) {
        int arow = t * 16 + l15;
        if (arow >= M) arow = M - 1;
        const _Float16* xp = X16 + (size_t)arow * H + q * 8;

        f16x8 xf[4];
#pragma unroll
        for (int c = 0; c < 4; c++) xf[c] = *(const f16x8*)(xp + c * 32);

        f32x4 a0 = {0.f,0.f,0.f,0.f}, a1 = a0, a2 = a0;
#pragma unroll
        for (int c = 0; c < 4; c++) {
            a0 = __builtin_amdgcn_mfma_f32_16x16x32_f16(xf[c], bf[0][c], a0, 0, 0, 0);
            a1 = __builtin_amdgcn_mfma_f32_16x16x32_f16(xf[c], bf[1][c], a1, 0, 0, 0);
            a2 = __builtin_amdgcn_mfma_f32_16x16x32_f16(xf[c], bf[2][c], a2, 0, 0, 0);
        }

#pragma unroll
        for (int rg = 0; rg < 4; rg++) {
            int row = t * 16 + q * 4 + rg;
            if (row < M) {
                Y [(size_t)row * H + col]      = a0[rg] + bj;
                Hh[(size_t)row * H + col]      = (_Float16)a1[rg];
                Hh[NH + (size_t)row * H + col] = (_Float16)a2[rg];
            }
        }
    }
}

// ---------------- mean-aggregate gather -------------------------------------------
// xn[dst] = fp16( y[dst] + sum_r mean(h_r[src]) ). One wave per dst row;
// 4 edges per iteration, 16B f16x8 loads; shfl_xor reduction across edge groups.
__global__ __launch_bounds__(256) void gather_mean(const float* __restrict__ Y,
    const _Float16* __restrict__ h, const int* __restrict__ elist,
    const int* __restrict__ cnt, _Float16* __restrict__ xn, int N, size_t NH)
{
    int wv = blockIdx.x * 4 + (threadIdx.x >> 6);
    int l  = threadIdx.x & 63;
    if (wv >= N) return;

    const int eo = l >> 4;          // edge slot 0..3
    const int c8 = (l & 15) * 8;    // 8-col group

    int d0r = cnt[wv], d1r = cnt[N + wv];
    int d0 = d0r < CAP ? d0r : CAP;
    int d1 = d1r < CAP ? d1r : CAP;
    float inv0 = d0r > 0 ? 1.f / (float)d0r : 0.f;
    float inv1 = d1r > 0 ? 1.f / (float)d1r : 0.f;
    const int* l0 = elist + (size_t)wv * CAP;
    const int* l1 = elist + ((size_t)N + wv) * CAP;
    int tot = d0 + d1;

    float acc[8];
#pragma unroll
    for (int j = 0; j < 8; j++) acc[j] = 0.f;

    for (int p = eo; p < tot; p += 4) {
        bool first = p < d0;
        int src   = first ? l0[p] : l1[p - d0];
        float sc  = first ? inv0 : inv1;
        size_t hb = first ? 0 : NH;
        f16x8 v = *(const f16x8*)&h[hb + (size_t)src * H + c8];
#pragma unroll
        for (int j = 0; j < 8; j++) acc[j] += sc * (float)v[j];
    }

#pragma unroll
    for (int j = 0; j < 8; j++) {
        acc[j] += __shfl_xor(acc[j], 16);
        acc[j] += __shfl_xor(acc[j], 32);
    }

    if (eo == 0) {
        float4 y0 = *(const float4*)&Y[(size_t)wv * H + c8];
        float4 y1 = *(const float4*)&Y[(size_t)wv * H + c8 + 4];
        f16x8 o;
        o[0] = (_Float16)(acc[0] + y0.x); o[1] = (_Float16)(acc[1] + y0.y);
        o[2] = (_Float16)(acc[2] + y0.z); o[3] = (_Float16)(acc[3] + y0.w);
        o[4] = (_Float16)(acc[4] + y1.x); o[5] = (_Float16)(acc[5] + y1.y);
        o[6] = (_Float16)(acc[6] + y1.z); o[7] = (_Float16)(acc[7] + y1.w);
        *(f16x8*)&xn[(size_t)wv * H + c8] = o;
    }
}

// ---------------- final projection: out[N,OUT] = X[N,128] @ Wo[128,OUT] + bo ------
__global__ __launch_bounds__(256) void out_gemm(const _Float16* __restrict__ X16,
    const float* __restrict__ Wo, const float* __restrict__ bo,
    float* __restrict__ out, int N, int OUT)
{
    int row = blockIdx.x * 4 + (threadIdx.x >> 6);
    int lane = threadIdx.x & 63;
    if (row >= N) return;
    float a0 = (float)X16[(size_t)row * H + lane];
    float a1 = (float)X16[(size_t)row * H + 64 + lane];
    for (int c = 0; c < OUT; c++) {
        float p = a0 * Wo[lane * OUT + c] + a1 * Wo[(64 + lane) * OUT + c];
        for (int off = 32; off > 0; off >>= 1) p += __shfl_down(p, off);
        if (lane == 0) out[(size_t)row * OUT + c] = p + bo[c];
    }
}

extern "C" void kernel_launch(void* const* d_in, const int* in_sizes, int n_in,
                              void* d_out, int out_size, void* d_ws, size_t ws_size,
                              hipStream_t stream) {
    const float* feature = (const float*)d_in[0];
    const int*   ei      = (const int*)d_in[1];   // [2,E]: src then dst
    const int*   et      = (const int*)d_in[2];   // [E]
    const float* w_in    = (const float*)d_in[3];
    const float* b_in    = (const float*)d_in[4];
    const float* w_rel   = (const float*)d_in[5];
    const float* w_root  = (const float*)d_in[6];
    const float* b_conv  = (const float*)d_in[7];
    const float* w_out   = (const float*)d_in[8];
    const float* b_out   = (const float*)d_in[9];

    const int HH   = in_sizes[4];                 // 128
    const int D_IN = in_sizes[3] / HH;            // 768
    const int N    = in_sizes[0] / D_IN;          // 50000
    const int E    = in_sizes[1] / 2;             // 600000
    const int R    = in_sizes[5] / (HH * HH);     // 2 (layout assumes 2)
    const int OUT  = in_sizes[9];                 // 3

    const size_t NH = (size_t)N * H;

    // workspace layout (16B-aligned segments)
    char* base = (char*)d_ws;
    _Float16* wInT = (_Float16*)base;                              // 128*K
    _Float16* w3T  = wInT + (size_t)D_IN * HH;                     // 3*128*128
    _Float16* x0   = w3T + (size_t)3 * HH * HH;                    // N*H fp16
    _Float16* x1   = x0 + NH;                                      // N*H fp16
    _Float16* h    = x1 + NH;                                      // R*N*H fp16
    float* y       = (float*)(h + (size_t)R * NH);                 // N*H fp32
    int* cnt       = (int*)(y + NH);                               // R*N
    int* elist     = cnt + (size_t)R * N;                          // R*N*CAP

    hipMemsetAsync(cnt, 0, sizeof(int) * (size_t)R * N, stream);
    prep_w<<<(D_IN * HH + 3 * HH * HH + 255) / 256, 256, 0, stream>>>(
        w_in, w_root, w_rel, wInT, w3T, D_IN);
    hist_fill<<<(E + 255) / 256, 256, 0, stream>>>(ei, ei + E, et, cnt, elist, E, N);

    const int mtiles = (N + 15) / 16;             // 3125 exact for N=50000
    // x0 = fp16(leakyrelu(feature @ w_in + b_in))
    gemm_big<<<1024, 512, 0, stream>>>(feature, wInT, b_in, x0, N, D_IN, mtiles);

    _Float16* xc = x0;
    _Float16* xo = x1;
    for (int layer = 0; layer < 2; layer++) {
        gemm3<<<1024, 256, 0, stream>>>(xc, w3T, b_conv, y, h, N, mtiles, NH);
        gather_mean<<<(N + 3) / 4, 256, 0, stream>>>(y, h, elist, cnt, xo, N, NH);
        _Float16* t = xc; xc = xo; xo = t;
    }

    out_gemm<<<(N + 3) / 4, 256, 0, stream>>>(xc, w_out, b_out, (float*)d_out, N, OUT);
}

// Round 7
// 464.759 us; speedup vs baseline: 1.4070x; 1.4070x over previous
//
#include <hip/hip_runtime.h>

#define H 128          // hidden dim (fixed by problem)
#define CAP 64         // max edges per (rel,dst) bucket

typedef _Float16 f16x8 __attribute__((ext_vector_type(8)));
typedef float    f32x4 __attribute__((ext_vector_type(4)));

// ---------------- edge bucketing: one pass, reused by both layers ----------------
__global__ __launch_bounds__(256) void hist_fill(const int* __restrict__ src,
    const int* __restrict__ dst, const int* __restrict__ et,
    int* __restrict__ cnt, int* __restrict__ elist, int E, int N)
{
    int e = blockIdx.x * 256 + threadIdx.x;
    if (e >= E) return;
    int s = src[e], d = dst[e], t = et[e];
    int b = t * N + d;
    int pos = atomicAdd(&cnt[b], 1);
    if (pos < CAP) elist[(size_t)b * CAP + pos] = s;
}

// ---------------- weight prep: transpose + fp32->fp16 ----------------
__global__ __launch_bounds__(256) void prep_w(const float* __restrict__ w_in,
    const float* __restrict__ w_root, const float* __restrict__ w_rel,
    _Float16* __restrict__ wInT, _Float16* __restrict__ w3T, int K)
{
    int idx = blockIdx.x * 256 + threadIdx.x;
    int tot1 = K * H;
    if (idx < tot1) {
        int c = idx / K, k = idx - c * K;
        wInT[idx] = (_Float16)w_in[(size_t)k * H + c];
    } else {
        int i2 = idx - tot1;
        if (i2 < 3 * H * H) {
            int m = i2 / (H * H), r2 = i2 - m * (H * H);
            int c = r2 >> 7, k = r2 & 127;
            const float* s = (m == 0) ? w_root : (w_rel + (size_t)(m - 1) * H * H);
            w3T[i2] = (_Float16)s[(size_t)k * H + c];
        }
    }
}

__device__ __forceinline__ f16x8 cvt8(float4 v0, float4 v1) {
    f16x8 t;
    t[0] = (_Float16)v0.x; t[1] = (_Float16)v0.y; t[2] = (_Float16)v0.z; t[3] = (_Float16)v0.w;
    t[4] = (_Float16)v1.x; t[5] = (_Float16)v1.y; t[6] = (_Float16)v1.z; t[7] = (_Float16)v1.w;
    return t;
}

// ---------------- big MFMA GEMM: LDS double-buffered, batched staging ------------
// C16 = fp16(leakyrelu(A[M,768] @ W + b)). Tile 64x128, BK=32, 4 waves (32x64
// quadrants). Per step each thread issues 4 INDEPENDENT 16B global loads
// (straight-line, regs only) for step s+1, computes step s from LDS, then
// writes s+1's regs to the other buffer. One barrier per step.
__global__ __launch_bounds__(256, 4) void gemm_big(const float* __restrict__ A,
    const _Float16* __restrict__ WT, const float* __restrict__ bias,
    _Float16* __restrict__ C16, int M, int K)
{
    __shared__ _Float16 As[2][64][40];    // stride 40 f16 = 80 B: 16B-aligned, 8 bank-quads
    __shared__ _Float16 Bs[2][128][40];

    const int tid = threadIdx.x;
    const int bm  = blockIdx.x * 64;
    const int w   = tid >> 6;
    const int l   = tid & 63;
    const int l15 = l & 15;
    const int q   = l >> 4;
    const int wr  = (w & 1) * 32;
    const int wc  = (w >> 1) * 64;

    // staging assignments (per thread, fixed for all steps)
    const int sar = tid >> 2;             // A row 0..63
    const int sak = (tid & 3) * 8;        // A k-offset (fp32 units)
    int sarow = bm + sar; if (sarow >= M) sarow = M - 1;
    const float* ap = A + (size_t)sarow * K + sak;
    const int sbc = tid >> 1;             // B col 0..127
    const int sbk = (tid & 1) * 16;       // B k-offset (f16 units)
    const _Float16* wp = WT + (size_t)sbc * K + sbk;

    f32x4 acc[2][4];
    const f32x4 z4 = {0.f, 0.f, 0.f, 0.f};
#pragma unroll
    for (int i = 0; i < 2; i++)
#pragma unroll
        for (int j = 0; j < 4; j++) acc[i][j] = z4;

    // prologue: stage step 0
    {
        float4 a0 = *(const float4*)(ap);
        float4 a1 = *(const float4*)(ap + 4);
        f16x8 b0  = *(const f16x8*)(wp);
        f16x8 b1  = *(const f16x8*)(wp + 8);
        *(f16x8*)&As[0][sar][sak]     = cvt8(a0, a1);
        *(f16x8*)&Bs[0][sbc][sbk]     = b0;
        *(f16x8*)&Bs[0][sbc][sbk + 8] = b1;
    }
    __syncthreads();

    const int steps = K / 32;             // 24
#pragma unroll 2
    for (int s = 0; s < steps; s++) {
        const int cur = s & 1;
        const bool more = (s + 1) < steps;
        float4 na0, na1; f16x8 nb0, nb1;
        if (more) {                        // 4 independent loads, in flight during MFMAs
            const int k0 = (s + 1) * 32;
            na0 = *(const float4*)(ap + k0);
            na1 = *(const float4*)(ap + k0 + 4);
            nb0 = *(const f16x8*)(wp + k0);
            nb1 = *(const f16x8*)(wp + k0 + 8);
        }
        // compute on buffer cur
        f16x8 af[2], bf[4];
#pragma unroll
        for (int i = 0; i < 2; i++) af[i] = *(const f16x8*)&As[cur][wr + i * 16 + l15][q * 8];
#pragma unroll
        for (int j = 0; j < 4; j++) bf[j] = *(const f16x8*)&Bs[cur][wc + j * 16 + l15][q * 8];
#pragma unroll
        for (int i = 0; i < 2; i++)
#pragma unroll
            for (int j = 0; j < 4; j++)
                acc[i][j] = __builtin_amdgcn_mfma_f32_16x16x32_f16(af[i], bf[j], acc[i][j], 0, 0, 0);
        if (more) {
            *(f16x8*)&As[cur ^ 1][sar][sak]     = cvt8(na0, na1);
            *(f16x8*)&Bs[cur ^ 1][sbc][sbk]     = nb0;
            *(f16x8*)&Bs[cur ^ 1][sbc][sbk + 8] = nb1;
        }
        __syncthreads();
    }

    // epilogue: bias + leaky, fp16 store
#pragma unroll
    for (int j = 0; j < 4; j++) {
        int col = wc + j * 16 + l15;
        float bj = bias[col];
#pragma unroll
        for (int i = 0; i < 2; i++)
#pragma unroll
            for (int rg = 0; rg < 4; rg++) {
                int row = bm + wr + i * 16 + q * 4 + rg;
                if (row < M) {
                    float v = acc[i][j][rg] + bj;
                    v = (v >= 0.f) ? v : 0.01f * v;
                    C16[(size_t)row * H + col] = (_Float16)v;
                }
            }
    }
}

// ---------------- fused per-layer GEMM: B3 in regs, x software-pipelined ----------
// y = x@w_root + b (fp32); h_r = x@w_rel[r] (fp16). 512 threads = 8 waves x 16
// cols (full 128). Grid-stride over 16-row tiles; next tile's x-frags loaded
// before current tile's MFMAs (small reg arrays -> promoted).
__global__ __launch_bounds__(512) void gemm3(const _Float16* __restrict__ X16,
    const _Float16* __restrict__ W3, const float* __restrict__ bias,
    float* __restrict__ Y, _Float16* __restrict__ Hh, int M, int mtiles,
    size_t NH)
{
    const int w   = threadIdx.x >> 6;
    const int l   = threadIdx.x & 63;
    const int l15 = l & 15;
    const int q   = l >> 4;
    const int col = w * 16 + l15;

    f16x8 bf[3][4];
#pragma unroll
    for (int m = 0; m < 3; m++) {
        const _Float16* wpp = W3 + (size_t)m * H * H + (size_t)col * H + q * 8;
#pragma unroll
        for (int c = 0; c < 4; c++) bf[m][c] = *(const f16x8*)(wpp + c * 32);
    }
    const float bj = bias[col];

    int t = blockIdx.x;
    if (t >= mtiles) return;
    f16x8 xf[4];
    {
        const _Float16* xp = X16 + ((size_t)t * 16 + l15) * H + q * 8;
#pragma unroll
        for (int c = 0; c < 4; c++) xf[c] = *(const f16x8*)(xp + c * 32);
    }

    const f32x4 z4 = {0.f, 0.f, 0.f, 0.f};
    while (true) {
        int tn = t + gridDim.x;
        bool more = tn < mtiles;
        f16x8 xnf[4];
        if (more) {
            const _Float16* xp = X16 + ((size_t)tn * 16 + l15) * H + q * 8;
#pragma unroll
            for (int c = 0; c < 4; c++) xnf[c] = *(const f16x8*)(xp + c * 32);
        }

        f32x4 a0 = z4, a1 = z4, a2 = z4;
#pragma unroll
        for (int c = 0; c < 4; c++) {
            a0 = __builtin_amdgcn_mfma_f32_16x16x32_f16(xf[c], bf[0][c], a0, 0, 0, 0);
            a1 = __builtin_amdgcn_mfma_f32_16x16x32_f16(xf[c], bf[1][c], a1, 0, 0, 0);
            a2 = __builtin_amdgcn_mfma_f32_16x16x32_f16(xf[c], bf[2][c], a2, 0, 0, 0);
        }

#pragma unroll
        for (int rg = 0; rg < 4; rg++) {
            int row = t * 16 + q * 4 + rg;
            if (row < M) {
                Y [(size_t)row * H + col]      = a0[rg] + bj;
                Hh[(size_t)row * H + col]      = (_Float16)a1[rg];
                Hh[NH + (size_t)row * H + col] = (_Float16)a2[rg];
            }
        }
        if (!more) break;
        t = tn;
#pragma unroll
        for (int c = 0; c < 4; c++) xf[c] = xnf[c];
    }
}

// ---------------- mean-aggregate gather -------------------------------------------
// xn[dst] = fp16( y[dst] + sum_r mean(h_r[src]) ). One wave per dst row.
// 4 edge slots x 16 col-lanes; per-lane DIRECT elist loads (same address within
// a slot group -> broadcast fetch; NO shfl in divergent flow — ds_bpermute
// returns 0 from inactive lanes, which silently corrupts. Learned round 6.)
// 2-deep unroll: two independent 16B h-row loads in flight.
__global__ __launch_bounds__(256) void gather_mean(const float* __restrict__ Y,
    const _Float16* __restrict__ h, const int* __restrict__ elist,
    const int* __restrict__ cnt, _Float16* __restrict__ xn, int N, size_t NH)
{
    int wv = blockIdx.x * 4 + (threadIdx.x >> 6);
    int l  = threadIdx.x & 63;
    if (wv >= N) return;

    int d0r = cnt[wv], d1r = cnt[N + wv];
    int d0 = d0r < CAP ? d0r : CAP;
    int d1 = d1r < CAP ? d1r : CAP;
    float inv0 = d0r > 0 ? 1.f / (float)d0r : 0.f;
    float inv1 = d1r > 0 ? 1.f / (float)d1r : 0.f;
    const int* l0 = elist + (size_t)wv * CAP;
    const int* l1 = elist + ((size_t)N + wv) * CAP;
    const int tot = d0 + d1;

    const int eo = l >> 4;          // edge slot 0..3
    const int c8 = (l & 15) * 8;    // 8-col group

    float acc[8];
#pragma unroll
    for (int j = 0; j < 8; j++) acc[j] = 0.f;

    for (int p = eo; p < tot; p += 8) {
        int pb = p + 4;
        bool fA = p < d0;
        int   sA  = fA ? l0[p] : l1[p - d0];
        float scA = fA ? inv0 : inv1;
        size_t hA = fA ? (size_t)0 : NH;
        f16x8 vA  = *(const f16x8*)&h[hA + (size_t)sA * H + c8];
        if (pb < tot) {
            bool fB = pb < d0;
            int   sB  = fB ? l0[pb] : l1[pb - d0];
            float scB = fB ? inv0 : inv1;
            size_t hB = fB ? (size_t)0 : NH;
            f16x8 vB  = *(const f16x8*)&h[hB + (size_t)sB * H + c8];
#pragma unroll
            for (int j = 0; j < 8; j++) acc[j] += scA * (float)vA[j] + scB * (float)vB[j];
        } else {
#pragma unroll
            for (int j = 0; j < 8; j++) acc[j] += scA * (float)vA[j];
        }
    }

    // convergent full-wave reduction across the 4 edge slots
#pragma unroll
    for (int j = 0; j < 8; j++) {
        acc[j] += __shfl_xor(acc[j], 16);
        acc[j] += __shfl_xor(acc[j], 32);
    }

    if (eo == 0) {
        float4 y0 = *(const float4*)&Y[(size_t)wv * H + c8];
        float4 y1 = *(const float4*)&Y[(size_t)wv * H + c8 + 4];
        f16x8 o;
        o[0] = (_Float16)(acc[0] + y0.x); o[1] = (_Float16)(acc[1] + y0.y);
        o[2] = (_Float16)(acc[2] + y0.z); o[3] = (_Float16)(acc[3] + y0.w);
        o[4] = (_Float16)(acc[4] + y1.x); o[5] = (_Float16)(acc[5] + y1.y);
        o[6] = (_Float16)(acc[6] + y1.z); o[7] = (_Float16)(acc[7] + y1.w);
        *(f16x8*)&xn[(size_t)wv * H + c8] = o;
    }
}

// ---------------- final projection: out[N,OUT] = X[N,128] @ Wo[128,OUT] + bo ------
__global__ __launch_bounds__(256) void out_gemm(const _Float16* __restrict__ X16,
    const float* __restrict__ Wo, const float* __restrict__ bo,
    float* __restrict__ out, int N, int OUT)
{
    int row = blockIdx.x * 4 + (threadIdx.x >> 6);
    int lane = threadIdx.x & 63;
    if (row >= N) return;
    float a0 = (float)X16[(size_t)row * H + lane];
    float a1 = (float)X16[(size_t)row * H + 64 + lane];
    for (int c = 0; c < OUT; c++) {
        float p = a0 * Wo[lane * OUT + c] + a1 * Wo[(64 + lane) * OUT + c];
        for (int off = 32; off > 0; off >>= 1) p += __shfl_down(p, off);
        if (lane == 0) out[(size_t)row * OUT + c] = p + bo[c];
    }
}

extern "C" void kernel_launch(void* const* d_in, const int* in_sizes, int n_in,
                              void* d_out, int out_size, void* d_ws, size_t ws_size,
                              hipStream_t stream) {
    const float* feature = (const float*)d_in[0];
    const int*   ei      = (const int*)d_in[1];   // [2,E]: src then dst
    const int*   et      = (const int*)d_in[2];   // [E]
    const float* w_in    = (const float*)d_in[3];
    const float* b_in    = (const float*)d_in[4];
    const float* w_rel   = (const float*)d_in[5];
    const float* w_root  = (const float*)d_in[6];
    const float* b_conv  = (const float*)d_in[7];
    const float* w_out   = (const float*)d_in[8];
    const float* b_out   = (const float*)d_in[9];

    const int HH   = in_sizes[4];                 // 128
    const int D_IN = in_sizes[3] / HH;            // 768
    const int N    = in_sizes[0] / D_IN;          // 50000
    const int E    = in_sizes[1] / 2;             // 600000
    const int R    = in_sizes[5] / (HH * HH);     // 2 (layout assumes 2)
    const int OUT  = in_sizes[9];                 // 3

    const size_t NH = (size_t)N * H;

    // workspace layout (16B-aligned segments)
    char* base = (char*)d_ws;
    _Float16* wInT = (_Float16*)base;                              // 128*K
    _Float16* w3T  = wInT + (size_t)D_IN * HH;                     // 3*128*128
    _Float16* x0   = w3T + (size_t)3 * HH * HH;                    // N*H fp16
    _Float16* x1   = x0 + NH;                                      // N*H fp16
    _Float16* h    = x1 + NH;                                      // R*N*H fp16
    float* y       = (float*)(h + (size_t)R * NH);                 // N*H fp32
    int* cnt       = (int*)(y + NH);                               // R*N
    int* elist     = cnt + (size_t)R * N;                          // R*N*CAP

    hipMemsetAsync(cnt, 0, sizeof(int) * (size_t)R * N, stream);
    prep_w<<<(D_IN * HH + 3 * HH * HH + 255) / 256, 256, 0, stream>>>(
        w_in, w_root, w_rel, wInT, w3T, D_IN);
    hist_fill<<<(E + 255) / 256, 256, 0, stream>>>(ei, ei + E, et, cnt, elist, E, N);

    // x0 = fp16(leakyrelu(feature @ w_in + b_in))
    gemm_big<<<(N + 63) / 64, 256, 0, stream>>>(feature, wInT, b_in, x0, N, D_IN);

    const int mtiles = (N + 15) / 16;             // 3125 exact for N=50000
    _Float16* xc = x0;
    _Float16* xo = x1;
    for (int layer = 0; layer < 2; layer++) {
        gemm3<<<1024, 512, 0, stream>>>(xc, w3T, b_conv, y, h, N, mtiles, NH);
        gather_mean<<<(N + 3) / 4, 256, 0, stream>>>(y, h, elist, cnt, xo, N, NH);
        _Float16* t = xc; xc = xo; xo = t;
    }

    out_gemm<<<(N + 3) / 4, 256, 0, stream>>>(xc, w_out, b_out, (float*)d_out, N, OUT);
}